// Round 7
// baseline (756.029 us; speedup 1.0000x reference)
//
#include <hip/hip_runtime.h>
#include <math.h>

namespace {

constexpr int B  = 4;
constexpr int C  = 512;     // qk_dim == v_dim
constexpr int L  = 4096;    // N == M
constexpr int LDK = 64;     // linear LDS row stride (f16 elems) for BK=64 tiles
constexpr float EPSI = 1e-5f;

typedef _Float16 f16x8 __attribute__((ext_vector_type(8)));
typedef short    sv8   __attribute__((ext_vector_type(8)));
typedef float    f32x4 __attribute__((ext_vector_type(4)));

__device__ inline unsigned short hfr(float x) {
  _Float16 h = (_Float16)x;
  return __builtin_bit_cast(unsigned short, h);
}
__device__ inline float h2f(unsigned short u) {
  return (float)__builtin_bit_cast(_Float16, u);
}

// async global->LDS, 16B per lane. LDS dest is wave-uniform base + lane*16;
// global address is per-lane (lets us pre-swizzle the source).
__device__ inline void gl_lds16(const unsigned short* g, unsigned short* lds) {
  __builtin_amdgcn_global_load_lds(
      (const __attribute__((address_space(1))) void*)g,
      (__attribute__((address_space(3))) void*)lds, 16, 0, 0);
}

// ---- XOR-swizzled tile layouts (both-sides involution, guide rule 21) ----
// BK=64:  [128 rows][8 chunks of 16B],  slot (row,cp) holds chunk cp ^ (row&7).
// BK=128: [128 rows][16 chunks of 16B], slot (row,cp) holds chunk cp ^ (row&15).
// Staging pre-swizzles the GLOBAL source so the linear HW write lands swizzled;
// ds_read applies the same XOR. VALIDATED r4: BANK_CONFLICT 25.2M -> 0.

// stage a 128x64 f16 tile (row stride rs elems in global) into swizzled LDS.
__device__ inline void stage16(const unsigned short* __restrict__ g, int rs,
                               unsigned short* lds, int t) {
  int lane = t & 63, wv = t >> 6;
  int r8 = lane >> 3;                 // row within 8-row segment == row&7
  int c8 = (lane & 7) ^ r8;           // pre-swizzled global chunk
  #pragma unroll
  for (int rep = 0; rep < 4; rep++) {
    int seg = wv * 4 + rep;
    gl_lds16(g + (size_t)(seg * 8 + r8) * rs + c8 * 8, lds + seg * 512);
  }
}

// ---------------- K0: W fp32 -> fp16 (once) ----------------
__global__ __launch_bounds__(256) void cvt_w_kernel(
    const float* __restrict__ Wq, const float* __restrict__ Wk,
    const float* __restrict__ Ws, unsigned short* __restrict__ Whq,
    unsigned short* __restrict__ Whk, unsigned short* __restrict__ Whs) {
  int y = blockIdx.y;
  const float* W = (y == 0) ? Wq : (y == 1) ? Wk : Ws;
  unsigned short* Wh = (y == 0) ? Whq : (y == 1) ? Whk : Whs;
  int i = blockIdx.x * 256 + threadIdx.x;          // float4 index, 512*512/4 = 65536
  float4 v = ((const float4*)W)[i];
  ((ushort4*)Wh)[i] = make_ushort4(hfr(v.x), hfr(v.y), hfr(v.z), hfr(v.w));
}

// ---------------- K1: per-(b,ch) mean / rstd for q, k, c ----------------
__global__ __launch_bounds__(256) void row_stats_kernel(
    const float* __restrict__ q, const float* __restrict__ k,
    const float* __restrict__ c, float* __restrict__ stats) {
  int row = blockIdx.x;                       // 0..6143 = arr*2048 + b*512 + ch
  const float* base = (row < 2048) ? q : (row < 4096 ? k : c);
  int r = row & 2047;
  const float4* x4 = (const float4*)(base + (size_t)r * L);
  float s = 0.f, ss = 0.f;
  for (int i = threadIdx.x; i < L / 4; i += 256) {
    float4 v = x4[i];
    s  += v.x + v.y + v.z + v.w;
    ss += v.x * v.x + v.y * v.y + v.z * v.z + v.w * v.w;
  }
  #pragma unroll
  for (int off = 32; off > 0; off >>= 1) {
    s  += __shfl_down(s, off, 64);
    ss += __shfl_down(ss, off, 64);
  }
  __shared__ float sh[8];
  int wid = threadIdx.x >> 6, lid = threadIdx.x & 63;
  if (lid == 0) { sh[wid * 2] = s; sh[wid * 2 + 1] = ss; }
  __syncthreads();
  if (threadIdx.x == 0) {
    float S  = sh[0] + sh[2] + sh[4] + sh[6];
    float SS = sh[1] + sh[3] + sh[5] + sh[7];
    float mean = S * (1.f / L);
    float var  = SS * (1.f / L) - mean * mean;
    stats[2 * row]     = mean;
    stats[2 * row + 1] = rsqrtf(var + EPSI);
  }
}

// ------- K2: transpose (+instance-norm for q,k) fp32[C][L] -> fp16[L][C] ----
// z = 0..11: arr = z>>2 (0=q,1=k,2=s), b = z&3. All 12 tensors in one launch.
__global__ __launch_bounds__(256) void transpose_all_kernel(
    const float* __restrict__ q, const float* __restrict__ k,
    const float* __restrict__ s, const float* __restrict__ stats,
    unsigned short* __restrict__ qT, unsigned short* __restrict__ kT,
    unsigned short* __restrict__ sT) {
  __shared__ unsigned short sh[64][66];   // padded: conflict-free column reads
  int z = blockIdx.z, arr = z >> 2, b = z & 3;
  const float* x = ((arr == 0) ? q : (arr == 1) ? k : s) + (size_t)b * C * L;
  unsigned short* xT = ((arr == 0) ? qT : (arr == 1) ? kT : sT) + (size_t)b * L * C;
  const float* stb = stats + (size_t)(arr * 2048 + b * 512) * 2;
  const bool norm = (arr < 2);
  int t = threadIdx.x;
  int i0 = blockIdx.x * 64, c0 = blockIdx.y * 64;
  #pragma unroll
  for (int rep = 0; rep < 4; rep++) {
    int cl = rep * 16 + (t >> 4);
    int f4 = t & 15;
    float4 v = *(const float4*)(x + (size_t)(c0 + cl) * L + i0 + f4 * 4);
    if (norm) {
      float mu = stb[2 * (c0 + cl)], rs = stb[2 * (c0 + cl) + 1];
      v.x = (v.x - mu) * rs; v.y = (v.y - mu) * rs;
      v.z = (v.z - mu) * rs; v.w = (v.w - mu) * rs;
    }
    *(ushort2*)&sh[cl][f4 * 4]     = make_ushort2(hfr(v.x), hfr(v.y));
    *(ushort2*)&sh[cl][f4 * 4 + 2] = make_ushort2(hfr(v.z), hfr(v.w));
  }
  __syncthreads();
  #pragma unroll
  for (int rr = 0; rr < 4; rr++) {
    int il = rr * 16 + (t >> 4);
    int cl = (t & 15) * 4;
    ushort4 o;
    o.x = sh[cl][il]; o.y = sh[cl + 1][il];
    o.z = sh[cl + 2][il]; o.w = sh[cl + 3][il];
    *(ushort4*)(xT + (size_t)(i0 + il) * C + c0 + cl) = o;
  }
}

// -------- shared MFMA inner blocks: 128x128 tile, 4 waves -------------------
// BK=64 reads: chunk = (ks*4+kq) ^ (row&7), row&7 == lm&7.

__device__ inline void mfma_block(const unsigned short* At, const unsigned short* Bt,
                                  f32x4 acc[4][4], int wm, int wn, int lm, int kq) {
  int sx = lm & 7;
  #pragma unroll
  for (int ks = 0; ks < 2; ks++) {
    int co = ((ks * 4 + kq) ^ sx) * 8;   // swizzled element offset within row
    f16x8 af[4], bf[4];
    #pragma unroll
    for (int i = 0; i < 4; i++)
      af[i] = __builtin_bit_cast(f16x8,
          *(const sv8*)&At[(wm + i * 16 + lm) * LDK + co]);
    #pragma unroll
    for (int j = 0; j < 4; j++)
      bf[j] = __builtin_bit_cast(f16x8,
          *(const sv8*)&Bt[(wn + j * 16 + lm) * LDK + co]);
    #pragma unroll
    for (int i = 0; i < 4; i++)
      #pragma unroll
      for (int j = 0; j < 4; j++)
        acc[i][j] = __builtin_amdgcn_mfma_f32_16x16x32_f16(af[i], bf[j], acc[i][j], 0, 0, 0);
  }
}

// BK=128 reads (LDW=128 elems/row): chunk = (ks*4+kq) ^ (row&15), row&15 == lm.
__device__ inline void mfma_blockw(const unsigned short* At, const unsigned short* Bt,
                                   f32x4 acc[4][4], int wm, int wn, int lm, int kq) {
  #pragma unroll
  for (int ks = 0; ks < 4; ks++) {
    int co = ((ks * 4 + kq) ^ lm) * 8;
    f16x8 af[4], bf[4];
    #pragma unroll
    for (int i = 0; i < 4; i++)
      af[i] = __builtin_bit_cast(f16x8,
          *(const sv8*)&At[(wm + i * 16 + lm) * 128 + co]);
    #pragma unroll
    for (int j = 0; j < 4; j++)
      bf[j] = __builtin_bit_cast(f16x8,
          *(const sv8*)&Bt[(wn + j * 16 + lm) * 128 + co]);
    #pragma unroll
    for (int i = 0; i < 4; i++)
      #pragma unroll
      for (int j = 0; j < 4; j++)
        acc[i][j] = __builtin_amdgcn_mfma_f32_16x16x32_f16(af[i], bf[j], acc[i][j], 0, 0, 0);
  }
}

// ---------------- K3: proj q/k fused: z=0..7 (b=z&3, which=z>>2) -----------
// outT[i][o] = sum_c xT[i][c]*W[o][c] + b[o]
__global__ __launch_bounds__(256) void proj_qk_all_kernel(
    const unsigned short* __restrict__ qT_all, const unsigned short* __restrict__ kT_all,
    const unsigned short* __restrict__ Whq, const unsigned short* __restrict__ Whk,
    const float* __restrict__ bq, const float* __restrict__ bk,
    unsigned short* __restrict__ qpT, unsigned short* __restrict__ kpT) {
  __shared__ __align__(16) unsigned short At[128 * LDK];
  __shared__ __align__(16) unsigned short Bt[128 * LDK];
  int z = blockIdx.z, b = z & 3, which = z >> 2;
  const unsigned short* xT = (which ? kT_all : qT_all) + (size_t)b * L * C;
  const unsigned short* Wh = which ? Whk : Whq;
  const float* bias = which ? bk : bq;
  unsigned short* outT = (which ? kpT : qpT) + (size_t)b * L * C;
  int t = threadIdx.x, lane = t & 63, wv = t >> 6;
  int lm = lane & 15, kq = lane >> 4;
  int wm = (wv >> 1) * 64, wn = (wv & 1) * 64;
  int i0 = blockIdx.x * 128, o0 = blockIdx.y * 128;
  f32x4 acc[4][4] = {};
  for (int kt = 0; kt < C / 64; kt++) {
    __syncthreads();
    stage16(xT + (size_t)i0 * C + kt * 64, C, At, t);
    stage16(Wh + (size_t)o0 * C + kt * 64, C, Bt, t);
    __syncthreads();
    mfma_block(At, Bt, acc, wm, wn, lm, kq);
  }
  #pragma unroll
  for (int j = 0; j < 4; j++) {
    int o = o0 + wn + j * 16 + lm;
    float bv = bias[o];
    #pragma unroll
    for (int i = 0; i < 4; i++)
      #pragma unroll
      for (int r = 0; r < 4; r++) {
        int irow = i0 + wm + i * 16 + kq * 4 + r;
        outT[(size_t)irow * C + o] = hfr(acc[i][j][r] + bv);
      }
  }
}

// ---------------- K4: proj s -> 4 planes (vh, vl, sqh, sql), z = b ----------
__global__ __launch_bounds__(256) void proj_s_all_kernel(
    const unsigned short* __restrict__ Whs, const unsigned short* __restrict__ sT_all,
    const float* __restrict__ bias, unsigned short* __restrict__ spp_all) {
  __shared__ __align__(16) unsigned short At[128 * LDK];
  __shared__ __align__(16) unsigned short Bt[128 * LDK];
  int b = blockIdx.z;
  const unsigned short* sT = sT_all + (size_t)b * L * C;
  unsigned short* spp = spp_all + (size_t)b * 4 * C * L;
  int t = threadIdx.x, lane = t & 63, wv = t >> 6;
  int lm = lane & 15, kq = lane >> 4;
  int wm = (wv >> 1) * 64, wn = (wv & 1) * 64;
  int j0 = blockIdx.x * 128, v0 = blockIdx.y * 128;
  const size_t PL = (size_t)C * L;
  f32x4 acc[4][4] = {};
  for (int kt = 0; kt < C / 64; kt++) {
    __syncthreads();
    stage16(Whs + (size_t)v0 * C + kt * 64, C, At, t);
    stage16(sT  + (size_t)j0 * C + kt * 64, C, Bt, t);
    __syncthreads();
    mfma_block(At, Bt, acc, wm, wn, lm, kq);
  }
  #pragma unroll
  for (int i = 0; i < 4; i++)
    #pragma unroll
    for (int r = 0; r < 4; r++) {
      int v = v0 + wm + i * 16 + kq * 4 + r;
      float bv = bias[v];
      #pragma unroll
      for (int j = 0; j < 4; j++) {
        int jc = j0 + wn + j * 16 + lm;
        float val = acc[i][j][r] + bv;
        float sq  = val * val;
        unsigned short vh = hfr(val);
        unsigned short vl = hfr(val - h2f(vh));
        unsigned short qh = hfr(sq);
        unsigned short ql = hfr(sq - h2f(qh));
        size_t off = (size_t)v * L + jc;
        spp[off]          = vh;
        spp[PL + off]     = vl;
        spp[2 * PL + off] = qh;
        spp[3 * PL + off] = ql;
      }
    }
}

// ---------------- K5: QK^T logits: Sc[il][j] = sum_c qpT[ibase+il][c]*kpT[j][c]
// XCD swizzle (T1): cluster the 32 j-blocks sharing one qpT A-panel onto one
// XCD (4 i-panels/XCD at itc=32) -> A panels + per-kt kpT slice stay in the
// 4MB per-XCD L2. Bijective when itc%8==0 (identity fallback otherwise).
__global__ __launch_bounds__(256) void qk_kernel(
    const unsigned short* __restrict__ qpT, const unsigned short* __restrict__ kpT,
    float* __restrict__ Sc, int ibase) {
  __shared__ __align__(16) unsigned short At[128 * LDK];
  __shared__ __align__(16) unsigned short Bt[128 * LDK];
  int t = threadIdx.x, lane = t & 63, wv = t >> 6;
  int lm = lane & 15, kq = lane >> 4;
  int wm = (wv >> 1) * 64, wn = (wv & 1) * 64;
  int j0i, i0i;
  {
    int itc = gridDim.y;                        // i-tiles (32 at n_ch=4096)
    int bid = blockIdx.x + gridDim.x * blockIdx.y;
    if ((itc & 7) == 0) {
      int xcd = bid & 7, slot = bid >> 3;       // slot in [0, 4*itc)
      i0i = (itc >> 3) * xcd + slot / 32;
      j0i = slot % 32;
    } else { j0i = blockIdx.x; i0i = blockIdx.y; }
  }
  int j0 = j0i * 128, i0 = i0i * 128;
  f32x4 acc[4][4] = {};
  for (int kt = 0; kt < C / 64; kt++) {
    __syncthreads();
    stage16(qpT + (size_t)(ibase + i0) * C + kt * 64, C, At, t);
    stage16(kpT + (size_t)j0 * C + kt * 64, C, Bt, t);
    __syncthreads();
    mfma_block(At, Bt, acc, wm, wn, lm, kq);
  }
  #pragma unroll
  for (int i = 0; i < 4; i++)
    #pragma unroll
    for (int r = 0; r < 4; r++) {
      int il = i0 + wm + i * 16 + kq * 4 + r;
      #pragma unroll
      for (int j = 0; j < 4; j++)
        Sc[(size_t)il * L + j0 + wn + j * 16 + lm] = acc[i][j][r];
    }
}

// -------- K6: row softmax over j; reads fp32 logits, writes fp16 probs ------
__global__ __launch_bounds__(256) void softmax_kernel(
    const float* __restrict__ Sc, unsigned short* __restrict__ Ph) {
  size_t row = blockIdx.x;
  const float4* s4 = (const float4*)(Sc + row * L);
  int t = threadIdx.x;
  float4 v[4];
  #pragma unroll
  for (int j = 0; j < 4; j++) v[j] = s4[t + 256 * j];
  float mx = -3.0e38f;
  #pragma unroll
  for (int j = 0; j < 4; j++)
    mx = fmaxf(mx, fmaxf(fmaxf(v[j].x, v[j].y), fmaxf(v[j].z, v[j].w)));
  #pragma unroll
  for (int off = 32; off > 0; off >>= 1) mx = fmaxf(mx, __shfl_down(mx, off, 64));
  __shared__ float sh[8];
  __shared__ float bc[2];
  int wid = t >> 6, lid = t & 63;
  if (lid == 0) sh[wid] = mx;
  __syncthreads();
  if (t == 0) bc[0] = fmaxf(fmaxf(sh[0], sh[1]), fmaxf(sh[2], sh[3]));
  __syncthreads();
  mx = bc[0];
  float sum = 0.f;
  #pragma unroll
  for (int j = 0; j < 4; j++) {
    v[j].x = __expf(v[j].x - mx); v[j].y = __expf(v[j].y - mx);
    v[j].z = __expf(v[j].z - mx); v[j].w = __expf(v[j].w - mx);
    sum += v[j].x + v[j].y + v[j].z + v[j].w;
  }
  #pragma unroll
  for (int off = 32; off > 0; off >>= 1) sum += __shfl_down(sum, off, 64);
  if (lid == 0) sh[4 + wid] = sum;
  __syncthreads();
  if (t == 0) bc[1] = 1.f / (sh[4] + sh[5] + sh[6] + sh[7]);
  __syncthreads();
  float inv = bc[1];
  #pragma unroll
  for (int j = 0; j < 4; j++) {
    ushort4 o = make_ushort4(hfr(v[j].x * inv), hfr(v[j].y * inv),
                             hfr(v[j].z * inv), hfr(v[j].w * inv));
    *(ushort4*)(Ph + row * L + (t + 256 * j) * 4) = o;
  }
}

// ---------------- K7: PV over 4 planes + fused finalize (BK=128) ----------
// A-tile rows lr: group g=lr>>4, plane p=g&3 (0=vh,1=vl,2=sqh,3=sql),
// v = v0 + ((g>>2)<<4) + (lr&15). Per-lane pre-swizzled global sources,
// hoisted out of the kt loop (kt-invariant base + kt*128 advance).
// XCD swizzle (T1): each XCD owns 2 v-groups x all i-tiles -> its spp A data
// (2MB) stays L2-resident across the whole kt loop, reused by 64 blocks.
// Single-buffer 2-barrier (r5: concurrent stage-writes contend with ds_reads).
__global__ __launch_bounds__(256) void pv_fin_kernel(
    const unsigned short* __restrict__ Ph, const unsigned short* __restrict__ spp,
    const float* __restrict__ cb, const float* __restrict__ stc,
    float* __restrict__ outb, int ibase) {
  __shared__ __align__(16) unsigned short At[128 * 128];   // 32KB
  __shared__ __align__(16) unsigned short Bt[128 * 128];   // 32KB
  int t = threadIdx.x, lane = t & 63, wv = t >> 6;
  int lm = lane & 15, kq = lane >> 4;
  int wm = (wv >> 1) * 64, wn = (wv & 1) * 64;
  int vg, it;
  {
    int itc = gridDim.y;                        // i-tiles
    int bid = blockIdx.x + gridDim.x * blockIdx.y;   // nwg = 16*itc, %8 == 0
    int xcd = bid & 7, slot = bid >> 3;         // slot in [0, 2*itc)
    vg = 2 * xcd + slot / itc;
    it = slot % itc;
  }
  int v0 = vg * 32;             // 32 actual v per block (x4 planes = 128 rows)
  int i0 = it * 128;
  // hoisted per-lane global source pointers (kt-invariant; +128 elems per kt)
  const unsigned short* asrc[8];
  const unsigned short* bsrc[8];
  {
    const size_t PL = (size_t)C * L;
    int r4 = lane >> 4;
    #pragma unroll
    for (int rep = 0; rep < 8; rep++) {
      int seg = wv * 8 + rep;
      int lr  = seg * 4 + r4;                   // tile row 0..127
      int g   = lr >> 4;
      int p   = g & 3;
      int vr  = v0 + ((g >> 2) << 4) + (lr & 15);
      int c16 = (lane & 15) ^ (lr & 15);        // pre-swizzled global chunk
      asrc[rep] = spp + (size_t)p * PL + (size_t)vr * L + c16 * 8;
      bsrc[rep] = Ph + (size_t)(i0 + lr) * L + c16 * 8;
    }
  }
  f32x4 acc[4][4] = {};
  for (int kt = 0; kt < L / 128; kt++) {
    __syncthreads();
    #pragma unroll
    for (int rep = 0; rep < 8; rep++) {
      int seg = wv * 8 + rep;
      gl_lds16(asrc[rep] + kt * 128, At + seg * 512);
      gl_lds16(bsrc[rep] + kt * 128, Bt + seg * 512);
    }
    __syncthreads();
    mfma_blockw(At, Bt, acc, wm, wn, lm, kq);
  }
  #pragma unroll
  for (int r = 0; r < 4; r++) {
    int v = v0 + (wm >> 2) + kq * 4 + r;         // wm=0 -> +0, wm=64 -> +16
    float mu = stc[2 * v], rs = stc[2 * v + 1];
    #pragma unroll
    for (int j = 0; j < 4; j++) {
      int ipos = ibase + i0 + wn + j * 16 + lm;
      float me = acc[0][j][r] + acc[1][j][r];
      float ms = acc[2][j][r] + acc[3][j][r];
      float sd = sqrtf(fmaxf(ms - me * me, 0.f));
      float cv = cb[(size_t)v * L + ipos];
      outb[(size_t)v * L + ipos] = (cv - mu) * rs * sd + me;
    }
  }
}

} // namespace

extern "C" void kernel_launch(void* const* d_in, const int* in_sizes, int n_in,
                              void* d_out, int out_size, void* d_ws, size_t ws_size,
                              hipStream_t stream) {
  const float* q  = (const float*)d_in[0];
  const float* k  = (const float*)d_in[1];
  const float* c  = (const float*)d_in[2];
  const float* s  = (const float*)d_in[3];
  const float* Wq = (const float*)d_in[4];
  const float* bq = (const float*)d_in[5];
  const float* Wk = (const float*)d_in[6];
  const float* bk = (const float*)d_in[7];
  const float* Ws = (const float*)d_in[8];
  const float* bs = (const float*)d_in[9];
  float* out = (float*)d_out;

  // workspace layout (bytes):
  //   qpT [B][L][C] f16 : 16 MB      @ 0
  //   kpT [B][L][C] f16 : 16 MB      @ 16777216
  //   spp [B][4][C][L]  : 64 MB      @ 33554432
  //   stats 6144*2 fp32 : 48 KB      @ 100663296
  //   scr @ 100712448:
  //     phase1: Wh (3x512KB) | qT/kT/sT all-batch (3x16MB)  -> top 152.6 MB
  //     phase2: Sc fp32 [n_ch][L] + Ph f16 [n_ch][L]        -> top 201.4 MB @4096
  char* wsb = (char*)d_ws;
  unsigned short* qpT = (unsigned short*)wsb;
  unsigned short* kpT = (unsigned short*)(wsb + 16777216);
  unsigned short* spp = (unsigned short*)(wsb + 33554432);
  float* stats        = (float*)(wsb + 100663296);
  char* scr           = wsb + 100712448;
  unsigned short* Whq = (unsigned short*)scr;
  unsigned short* Whk = Whq + 262144;
  unsigned short* Whs = Whk + 262144;
  unsigned short* qT_all = (unsigned short*)(scr + 1572864);
  unsigned short* kT_all = qT_all + (size_t)B * L * C;
  unsigned short* sT_all = kT_all + (size_t)B * L * C;

  size_t avail = ws_size > 100712448ULL ? ws_size - 100712448ULL : 0;
  int n_ch = 256;
  const int cands[5] = {4096, 2048, 1024, 512, 256};
  for (int ci = 0; ci < 5; ci++)
    if ((size_t)cands[ci] * L * 6 <= avail) { n_ch = cands[ci]; break; }
  float* Sc          = (float*)scr;                          // [n_ch][L] fp32
  unsigned short* Ph = (unsigned short*)(scr + (size_t)n_ch * L * 4);  // f16

  // ---- phase 1: stats, W convert, transposes, projections (all batch-fused)
  cvt_w_kernel<<<dim3(256, 3), 256, 0, stream>>>(Wq, Wk, Ws, Whq, Whk, Whs);
  row_stats_kernel<<<6144, 256, 0, stream>>>(q, k, c, stats);
  transpose_all_kernel<<<dim3(64, 8, 12), 256, 0, stream>>>(
      q, k, s, stats, qT_all, kT_all, sT_all);
  proj_qk_all_kernel<<<dim3(32, 4, 8), 256, 0, stream>>>(
      qT_all, kT_all, Whq, Whk, bq, bk, qpT, kpT);
  proj_s_all_kernel<<<dim3(32, 4, 4), 256, 0, stream>>>(Whs, sT_all, bs, spp);

  // ---- phase 2: attention (per batch, chunked over i) ----
  const size_t sppB = (size_t)4 * C * L;   // per-batch spp stride (elements)
  for (int b = 0; b < B; b++) {
    for (int ibase = 0; ibase < L; ibase += n_ch) {
      qk_kernel<<<dim3(32, n_ch / 128), 256, 0, stream>>>(
          qpT + (size_t)b * L * C, kpT + (size_t)b * L * C, Sc, ibase);
      softmax_kernel<<<n_ch, 256, 0, stream>>>(Sc, Ph);
      pv_fin_kernel<<<dim3(16, n_ch / 128), 256, 0, stream>>>(
          Ph, spp + (size_t)b * sppB, c + (size_t)b * C * L,
          stats + 8192 + (size_t)b * C * 2, out + (size_t)b * C * L, ibase);
    }
  }
}

// Round 8
// 704.437 us; speedup vs baseline: 1.0732x; 1.0732x over previous
//
#include <hip/hip_runtime.h>
#include <math.h>

namespace {

constexpr int B  = 4;
constexpr int C  = 512;     // qk_dim == v_dim
constexpr int L  = 4096;    // N == M
constexpr int LDK = 64;     // linear LDS row stride (f16 elems) for BK=64 tiles
constexpr float EPSI = 1e-5f;

typedef _Float16 f16x8 __attribute__((ext_vector_type(8)));
typedef short    sv8   __attribute__((ext_vector_type(8)));
typedef float    f32x4 __attribute__((ext_vector_type(4)));

__device__ inline unsigned short hfr(float x) {
  _Float16 h = (_Float16)x;
  return __builtin_bit_cast(unsigned short, h);
}
__device__ inline float h2f(unsigned short u) {
  return (float)__builtin_bit_cast(_Float16, u);
}

// async global->LDS, 16B per lane. LDS dest is wave-uniform base + lane*16;
// global address is per-lane (lets us pre-swizzle the source).
__device__ inline void gl_lds16(const unsigned short* g, unsigned short* lds) {
  __builtin_amdgcn_global_load_lds(
      (const __attribute__((address_space(1))) void*)g,
      (__attribute__((address_space(3))) void*)lds, 16, 0, 0);
}

// ---- XOR-swizzled tile layouts (both-sides involution, guide rule 21) ----
// BK=64:  [128 rows][8 chunks of 16B],  slot (row,cp) holds chunk cp ^ (row&7).
// BK=128: [128 rows][16 chunks of 16B], slot (row,cp) holds chunk cp ^ (row&15).
// Staging pre-swizzles the GLOBAL source so the linear HW write lands swizzled;
// ds_read applies the same XOR. VALIDATED r4: BANK_CONFLICT 25.2M -> 0.

// stage a 128x64 f16 tile (row stride rs elems in global) into swizzled LDS.
__device__ inline void stage16(const unsigned short* __restrict__ g, int rs,
                               unsigned short* lds, int t) {
  int lane = t & 63, wv = t >> 6;
  int r8 = lane >> 3;                 // row within 8-row segment == row&7
  int c8 = (lane & 7) ^ r8;           // pre-swizzled global chunk
  #pragma unroll
  for (int rep = 0; rep < 4; rep++) {
    int seg = wv * 4 + rep;
    gl_lds16(g + (size_t)(seg * 8 + r8) * rs + c8 * 8, lds + seg * 512);
  }
}

// stage a 128x128 f16 tile (row stride rs) into swizzled LDS (BK=128 layout).
// Segment = 4 rows x 256B; lane l: row seg*4 + (l>>4), phys chunk l&15,
// global chunk (l&15) ^ (row&15).
__device__ inline void stage16w(const unsigned short* __restrict__ g, int rs,
                                unsigned short* lds, int t) {
  int lane = t & 63, wv = t >> 6;
  int r4 = lane >> 4;
  #pragma unroll
  for (int rep = 0; rep < 8; rep++) {
    int seg = wv * 8 + rep;
    int row = seg * 4 + r4;
    int c16 = (lane & 15) ^ (row & 15);
    gl_lds16(g + (size_t)row * rs + c16 * 8, lds + seg * 512);
  }
}

// ---------------- K0: W fp32 -> fp16 (once) ----------------
__global__ __launch_bounds__(256) void cvt_w_kernel(
    const float* __restrict__ Wq, const float* __restrict__ Wk,
    const float* __restrict__ Ws, unsigned short* __restrict__ Whq,
    unsigned short* __restrict__ Whk, unsigned short* __restrict__ Whs) {
  int y = blockIdx.y;
  const float* W = (y == 0) ? Wq : (y == 1) ? Wk : Ws;
  unsigned short* Wh = (y == 0) ? Whq : (y == 1) ? Whk : Whs;
  int i = blockIdx.x * 256 + threadIdx.x;          // float4 index, 512*512/4 = 65536
  float4 v = ((const float4*)W)[i];
  ((ushort4*)Wh)[i] = make_ushort4(hfr(v.x), hfr(v.y), hfr(v.z), hfr(v.w));
}

// ---------------- K1: per-(b,ch) mean / rstd for q, k, c ----------------
__global__ __launch_bounds__(256) void row_stats_kernel(
    const float* __restrict__ q, const float* __restrict__ k,
    const float* __restrict__ c, float* __restrict__ stats) {
  int row = blockIdx.x;                       // 0..6143 = arr*2048 + b*512 + ch
  const float* base = (row < 2048) ? q : (row < 4096 ? k : c);
  int r = row & 2047;
  const float4* x4 = (const float4*)(base + (size_t)r * L);
  float s = 0.f, ss = 0.f;
  for (int i = threadIdx.x; i < L / 4; i += 256) {
    float4 v = x4[i];
    s  += v.x + v.y + v.z + v.w;
    ss += v.x * v.x + v.y * v.y + v.z * v.z + v.w * v.w;
  }
  #pragma unroll
  for (int off = 32; off > 0; off >>= 1) {
    s  += __shfl_down(s, off, 64);
    ss += __shfl_down(ss, off, 64);
  }
  __shared__ float sh[8];
  int wid = threadIdx.x >> 6, lid = threadIdx.x & 63;
  if (lid == 0) { sh[wid * 2] = s; sh[wid * 2 + 1] = ss; }
  __syncthreads();
  if (threadIdx.x == 0) {
    float S  = sh[0] + sh[2] + sh[4] + sh[6];
    float SS = sh[1] + sh[3] + sh[5] + sh[7];
    float mean = S * (1.f / L);
    float var  = SS * (1.f / L) - mean * mean;
    stats[2 * row]     = mean;
    stats[2 * row + 1] = rsqrtf(var + EPSI);
  }
}

// ------- K2: transpose (+instance-norm for q,k) fp32[C][L] -> fp16[L][C] ----
// z = 0..11: arr = z>>2 (0=q,1=k,2=s), b = z&3. All 12 tensors in one launch.
__global__ __launch_bounds__(256) void transpose_all_kernel(
    const float* __restrict__ q, const float* __restrict__ k,
    const float* __restrict__ s, const float* __restrict__ stats,
    unsigned short* __restrict__ qT, unsigned short* __restrict__ kT,
    unsigned short* __restrict__ sT) {
  __shared__ unsigned short sh[64][66];   // padded: conflict-free column reads
  int z = blockIdx.z, arr = z >> 2, b = z & 3;
  const float* x = ((arr == 0) ? q : (arr == 1) ? k : s) + (size_t)b * C * L;
  unsigned short* xT = ((arr == 0) ? qT : (arr == 1) ? kT : sT) + (size_t)b * L * C;
  const float* stb = stats + (size_t)(arr * 2048 + b * 512) * 2;
  const bool norm = (arr < 2);
  int t = threadIdx.x;
  int i0 = blockIdx.x * 64, c0 = blockIdx.y * 64;
  #pragma unroll
  for (int rep = 0; rep < 4; rep++) {
    int cl = rep * 16 + (t >> 4);
    int f4 = t & 15;
    float4 v = *(const float4*)(x + (size_t)(c0 + cl) * L + i0 + f4 * 4);
    if (norm) {
      float mu = stb[2 * (c0 + cl)], rs = stb[2 * (c0 + cl) + 1];
      v.x = (v.x - mu) * rs; v.y = (v.y - mu) * rs;
      v.z = (v.z - mu) * rs; v.w = (v.w - mu) * rs;
    }
    *(ushort2*)&sh[cl][f4 * 4]     = make_ushort2(hfr(v.x), hfr(v.y));
    *(ushort2*)&sh[cl][f4 * 4 + 2] = make_ushort2(hfr(v.z), hfr(v.w));
  }
  __syncthreads();
  #pragma unroll
  for (int rr = 0; rr < 4; rr++) {
    int il = rr * 16 + (t >> 4);
    int cl = (t & 15) * 4;
    ushort4 o;
    o.x = sh[cl][il]; o.y = sh[cl + 1][il];
    o.z = sh[cl + 2][il]; o.w = sh[cl + 3][il];
    *(ushort4*)(xT + (size_t)(i0 + il) * C + c0 + cl) = o;
  }
}

// -------- shared MFMA inner blocks: 128x128 tile, 4 waves -------------------
// BK=64 reads: chunk = (ks*4+kq) ^ (row&7), row&7 == lm&7.

__device__ inline void mfma_block(const unsigned short* At, const unsigned short* Bt,
                                  f32x4 acc[4][4], int wm, int wn, int lm, int kq) {
  int sx = lm & 7;
  #pragma unroll
  for (int ks = 0; ks < 2; ks++) {
    int co = ((ks * 4 + kq) ^ sx) * 8;   // swizzled element offset within row
    f16x8 af[4], bf[4];
    #pragma unroll
    for (int i = 0; i < 4; i++)
      af[i] = __builtin_bit_cast(f16x8,
          *(const sv8*)&At[(wm + i * 16 + lm) * LDK + co]);
    #pragma unroll
    for (int j = 0; j < 4; j++)
      bf[j] = __builtin_bit_cast(f16x8,
          *(const sv8*)&Bt[(wn + j * 16 + lm) * LDK + co]);
    #pragma unroll
    for (int i = 0; i < 4; i++)
      #pragma unroll
      for (int j = 0; j < 4; j++)
        acc[i][j] = __builtin_amdgcn_mfma_f32_16x16x32_f16(af[i], bf[j], acc[i][j], 0, 0, 0);
  }
}

// BK=128 reads (LDW=128 elems/row): chunk = (ks*4+kq) ^ (row&15), row&15 == lm.
__device__ inline void mfma_blockw(const unsigned short* At, const unsigned short* Bt,
                                   f32x4 acc[4][4], int wm, int wn, int lm, int kq) {
  #pragma unroll
  for (int ks = 0; ks < 4; ks++) {
    int co = ((ks * 4 + kq) ^ lm) * 8;
    f16x8 af[4], bf[4];
    #pragma unroll
    for (int i = 0; i < 4; i++)
      af[i] = __builtin_bit_cast(f16x8,
          *(const sv8*)&At[(wm + i * 16 + lm) * 128 + co]);
    #pragma unroll
    for (int j = 0; j < 4; j++)
      bf[j] = __builtin_bit_cast(f16x8,
          *(const sv8*)&Bt[(wn + j * 16 + lm) * 128 + co]);
    #pragma unroll
    for (int i = 0; i < 4; i++)
      #pragma unroll
      for (int j = 0; j < 4; j++)
        acc[i][j] = __builtin_amdgcn_mfma_f32_16x16x32_f16(af[i], bf[j], acc[i][j], 0, 0, 0);
  }
}

// ---------------- K3: proj q/k fused: z=0..7 (b=z&3, which=z>>2) -----------
// outT[i][o] = sum_c xT[i][c]*W[o][c] + b[o]
__global__ __launch_bounds__(256) void proj_qk_all_kernel(
    const unsigned short* __restrict__ qT_all, const unsigned short* __restrict__ kT_all,
    const unsigned short* __restrict__ Whq, const unsigned short* __restrict__ Whk,
    const float* __restrict__ bq, const float* __restrict__ bk,
    unsigned short* __restrict__ qpT, unsigned short* __restrict__ kpT) {
  __shared__ __align__(16) unsigned short At[128 * LDK];
  __shared__ __align__(16) unsigned short Bt[128 * LDK];
  int z = blockIdx.z, b = z & 3, which = z >> 2;
  const unsigned short* xT = (which ? kT_all : qT_all) + (size_t)b * L * C;
  const unsigned short* Wh = which ? Whk : Whq;
  const float* bias = which ? bk : bq;
  unsigned short* outT = (which ? kpT : qpT) + (size_t)b * L * C;
  int t = threadIdx.x, lane = t & 63, wv = t >> 6;
  int lm = lane & 15, kq = lane >> 4;
  int wm = (wv >> 1) * 64, wn = (wv & 1) * 64;
  int i0 = blockIdx.x * 128, o0 = blockIdx.y * 128;
  f32x4 acc[4][4] = {};
  for (int kt = 0; kt < C / 64; kt++) {
    __syncthreads();
    stage16(xT + (size_t)i0 * C + kt * 64, C, At, t);
    stage16(Wh + (size_t)o0 * C + kt * 64, C, Bt, t);
    __syncthreads();
    mfma_block(At, Bt, acc, wm, wn, lm, kq);
  }
  #pragma unroll
  for (int j = 0; j < 4; j++) {
    int o = o0 + wn + j * 16 + lm;
    float bv = bias[o];
    #pragma unroll
    for (int i = 0; i < 4; i++)
      #pragma unroll
      for (int r = 0; r < 4; r++) {
        int irow = i0 + wm + i * 16 + kq * 4 + r;
        outT[(size_t)irow * C + o] = hfr(acc[i][j][r] + bv);
      }
  }
}

// ---------------- K4: proj s -> 4 planes (vh, vl, sqh, sql), z = b ----------
__global__ __launch_bounds__(256) void proj_s_all_kernel(
    const unsigned short* __restrict__ Whs, const unsigned short* __restrict__ sT_all,
    const float* __restrict__ bias, unsigned short* __restrict__ spp_all) {
  __shared__ __align__(16) unsigned short At[128 * LDK];
  __shared__ __align__(16) unsigned short Bt[128 * LDK];
  int b = blockIdx.z;
  const unsigned short* sT = sT_all + (size_t)b * L * C;
  unsigned short* spp = spp_all + (size_t)b * 4 * C * L;
  int t = threadIdx.x, lane = t & 63, wv = t >> 6;
  int lm = lane & 15, kq = lane >> 4;
  int wm = (wv >> 1) * 64, wn = (wv & 1) * 64;
  int j0 = blockIdx.x * 128, v0 = blockIdx.y * 128;
  const size_t PL = (size_t)C * L;
  f32x4 acc[4][4] = {};
  for (int kt = 0; kt < C / 64; kt++) {
    __syncthreads();
    stage16(Whs + (size_t)v0 * C + kt * 64, C, At, t);
    stage16(sT  + (size_t)j0 * C + kt * 64, C, Bt, t);
    __syncthreads();
    mfma_block(At, Bt, acc, wm, wn, lm, kq);
  }
  #pragma unroll
  for (int i = 0; i < 4; i++)
    #pragma unroll
    for (int r = 0; r < 4; r++) {
      int v = v0 + wm + i * 16 + kq * 4 + r;
      float bv = bias[v];
      #pragma unroll
      for (int j = 0; j < 4; j++) {
        int jc = j0 + wn + j * 16 + lm;
        float val = acc[i][j][r] + bv;
        float sq  = val * val;
        unsigned short vh = hfr(val);
        unsigned short vl = hfr(val - h2f(vh));
        unsigned short qh = hfr(sq);
        unsigned short ql = hfr(sq - h2f(qh));
        size_t off = (size_t)v * L + jc;
        spp[off]          = vh;
        spp[PL + off]     = vl;
        spp[2 * PL + off] = qh;
        spp[3 * PL + off] = ql;
      }
    }
}

// ---------------- K5: QK^T logits: Sc[il][j] = sum_c qpT[ibase+il][c]*kpT[j][c]
__global__ __launch_bounds__(256) void qk_kernel(
    const unsigned short* __restrict__ qpT, const unsigned short* __restrict__ kpT,
    float* __restrict__ Sc, int ibase) {
  __shared__ __align__(16) unsigned short At[128 * LDK];
  __shared__ __align__(16) unsigned short Bt[128 * LDK];
  int t = threadIdx.x, lane = t & 63, wv = t >> 6;
  int lm = lane & 15, kq = lane >> 4;
  int wm = (wv >> 1) * 64, wn = (wv & 1) * 64;
  int j0 = blockIdx.x * 128, i0 = blockIdx.y * 128;
  f32x4 acc[4][4] = {};
  for (int kt = 0; kt < C / 64; kt++) {
    __syncthreads();
    stage16(qpT + (size_t)(ibase + i0) * C + kt * 64, C, At, t);
    stage16(kpT + (size_t)j0 * C + kt * 64, C, Bt, t);
    __syncthreads();
    mfma_block(At, Bt, acc, wm, wn, lm, kq);
  }
  #pragma unroll
  for (int i = 0; i < 4; i++)
    #pragma unroll
    for (int r = 0; r < 4; r++) {
      int il = i0 + wm + i * 16 + kq * 4 + r;
      #pragma unroll
      for (int j = 0; j < 4; j++)
        Sc[(size_t)il * L + j0 + wn + j * 16 + lm] = acc[i][j][r];
    }
}

// -------- K6: row softmax over j; reads fp32 logits, writes fp16 probs ------
__global__ __launch_bounds__(256) void softmax_kernel(
    const float* __restrict__ Sc, unsigned short* __restrict__ Ph) {
  size_t row = blockIdx.x;
  const float4* s4 = (const float4*)(Sc + row * L);
  int t = threadIdx.x;
  float4 v[4];
  #pragma unroll
  for (int j = 0; j < 4; j++) v[j] = s4[t + 256 * j];
  float mx = -3.0e38f;
  #pragma unroll
  for (int j = 0; j < 4; j++)
    mx = fmaxf(mx, fmaxf(fmaxf(v[j].x, v[j].y), fmaxf(v[j].z, v[j].w)));
  #pragma unroll
  for (int off = 32; off > 0; off >>= 1) mx = fmaxf(mx, __shfl_down(mx, off, 64));
  __shared__ float sh[8];
  __shared__ float bc[2];
  int wid = t >> 6, lid = t & 63;
  if (lid == 0) sh[wid] = mx;
  __syncthreads();
  if (t == 0) bc[0] = fmaxf(fmaxf(sh[0], sh[1]), fmaxf(sh[2], sh[3]));
  __syncthreads();
  mx = bc[0];
  float sum = 0.f;
  #pragma unroll
  for (int j = 0; j < 4; j++) {
    v[j].x = __expf(v[j].x - mx); v[j].y = __expf(v[j].y - mx);
    v[j].z = __expf(v[j].z - mx); v[j].w = __expf(v[j].w - mx);
    sum += v[j].x + v[j].y + v[j].z + v[j].w;
  }
  #pragma unroll
  for (int off = 32; off > 0; off >>= 1) sum += __shfl_down(sum, off, 64);
  if (lid == 0) sh[4 + wid] = sum;
  __syncthreads();
  if (t == 0) bc[1] = 1.f / (sh[4] + sh[5] + sh[6] + sh[7]);
  __syncthreads();
  float inv = bc[1];
  #pragma unroll
  for (int j = 0; j < 4; j++) {
    ushort4 o = make_ushort4(hfr(v[j].x * inv), hfr(v[j].y * inv),
                             hfr(v[j].z * inv), hfr(v[j].w * inv));
    *(ushort4*)(Ph + row * L + (t + 256 * j) * 4) = o;
  }
}

// ---------------- K7: PV over 4 planes + fused finalize (BK=128) ----------
// A-tile rows lr: group g=lr>>4, plane p=g&3 (0=vh,1=vl,2=sqh,3=sql),
// v = v0 + ((g>>2)<<4) + (lr&15). Per-lane global gather, pre-swizzled source
// (16-chunk XOR). Single-buffer 2-barrier (r5: concurrent stage-writes contend
// with ds_reads; r7: XCD swizzle + pointer hoisting both regressed — reverted).
// T5 setprio around the compute phase: 2 anti-phase blocks/CU -> the MFMA-ing
// block's waves win issue arbitration over the staging block's (m191 regime).
__device__ inline void stage_sppw(const unsigned short* __restrict__ spp_b, int v0,
                                  int kbase, unsigned short* At, int t) {
  const size_t PL = (size_t)C * L;
  int lane = t & 63, wv = t >> 6;
  int r4 = lane >> 4;
  #pragma unroll
  for (int rep = 0; rep < 8; rep++) {
    int seg = wv * 8 + rep;
    int lr  = seg * 4 + r4;
    int g   = lr >> 4;
    int p   = g & 3;
    int vr  = v0 + ((g >> 2) << 4) + (lr & 15);
    int c16 = (lane & 15) ^ (lr & 15);
    gl_lds16(spp_b + (size_t)p * PL + (size_t)vr * L + kbase + c16 * 8,
             At + seg * 512);
  }
}

__global__ __launch_bounds__(256) void pv_fin_kernel(
    const unsigned short* __restrict__ Ph, const unsigned short* __restrict__ spp,
    const float* __restrict__ cb, const float* __restrict__ stc,
    float* __restrict__ outb, int ibase) {
  __shared__ __align__(16) unsigned short At[128 * 128];   // 32KB
  __shared__ __align__(16) unsigned short Bt[128 * 128];   // 32KB
  int t = threadIdx.x, lane = t & 63, wv = t >> 6;
  int lm = lane & 15, kq = lane >> 4;
  int wm = (wv >> 1) * 64, wn = (wv & 1) * 64;
  int v0 = blockIdx.x * 32;     // 32 actual v per block (x4 planes = 128 rows)
  int i0 = blockIdx.y * 128;
  f32x4 acc[4][4] = {};
  for (int kt = 0; kt < L / 128; kt++) {
    __syncthreads();
    stage_sppw(spp, v0, kt * 128, At, t);
    stage16w(Ph + (size_t)i0 * L + kt * 128, L, Bt, t);
    __syncthreads();
    __builtin_amdgcn_s_setprio(1);
    mfma_blockw(At, Bt, acc, wm, wn, lm, kq);
    __builtin_amdgcn_s_setprio(0);
  }
  #pragma unroll
  for (int r = 0; r < 4; r++) {
    int v = v0 + (wm >> 2) + kq * 4 + r;         // wm=0 -> +0, wm=64 -> +16
    float mu = stc[2 * v], rs = stc[2 * v + 1];
    #pragma unroll
    for (int j = 0; j < 4; j++) {
      int ipos = ibase + i0 + wn + j * 16 + lm;
      float me = acc[0][j][r] + acc[1][j][r];
      float ms = acc[2][j][r] + acc[3][j][r];
      float sd = sqrtf(fmaxf(ms - me * me, 0.f));
      float cv = cb[(size_t)v * L + ipos];
      outb[(size_t)v * L + ipos] = (cv - mu) * rs * sd + me;
    }
  }
}

} // namespace

extern "C" void kernel_launch(void* const* d_in, const int* in_sizes, int n_in,
                              void* d_out, int out_size, void* d_ws, size_t ws_size,
                              hipStream_t stream) {
  const float* q  = (const float*)d_in[0];
  const float* k  = (const float*)d_in[1];
  const float* c  = (const float*)d_in[2];
  const float* s  = (const float*)d_in[3];
  const float* Wq = (const float*)d_in[4];
  const float* bq = (const float*)d_in[5];
  const float* Wk = (const float*)d_in[6];
  const float* bk = (const float*)d_in[7];
  const float* Ws = (const float*)d_in[8];
  const float* bs = (const float*)d_in[9];
  float* out = (float*)d_out;

  // workspace layout (bytes):
  //   qpT [B][L][C] f16 : 16 MB      @ 0
  //   kpT [B][L][C] f16 : 16 MB      @ 16777216
  //   spp [B][4][C][L]  : 64 MB      @ 33554432
  //   stats 6144*2 fp32 : 48 KB      @ 100663296
  //   scr @ 100712448:
  //     phase1: Wh (3x512KB) | qT/kT/sT all-batch (3x16MB)  -> top 152.6 MB
  //     phase2: Sc fp32 [n_ch][L] + Ph f16 [n_ch][L]        -> top 201.4 MB @4096
  char* wsb = (char*)d_ws;
  unsigned short* qpT = (unsigned short*)wsb;
  unsigned short* kpT = (unsigned short*)(wsb + 16777216);
  unsigned short* spp = (unsigned short*)(wsb + 33554432);
  float* stats        = (float*)(wsb + 100663296);
  char* scr           = wsb + 100712448;
  unsigned short* Whq = (unsigned short*)scr;
  unsigned short* Whk = Whq + 262144;
  unsigned short* Whs = Whk + 262144;
  unsigned short* qT_all = (unsigned short*)(scr + 1572864);
  unsigned short* kT_all = qT_all + (size_t)B * L * C;
  unsigned short* sT_all = kT_all + (size_t)B * L * C;

  size_t avail = ws_size > 100712448ULL ? ws_size - 100712448ULL : 0;
  int n_ch = 256;
  const int cands[5] = {4096, 2048, 1024, 512, 256};
  for (int ci = 0; ci < 5; ci++)
    if ((size_t)cands[ci] * L * 6 <= avail) { n_ch = cands[ci]; break; }
  float* Sc          = (float*)scr;                          // [n_ch][L] fp32
  unsigned short* Ph = (unsigned short*)(scr + (size_t)n_ch * L * 4);  // f16

  // ---- phase 1: stats, W convert, transposes, projections (all batch-fused)
  cvt_w_kernel<<<dim3(256, 3), 256, 0, stream>>>(Wq, Wk, Ws, Whq, Whk, Whs);
  row_stats_kernel<<<6144, 256, 0, stream>>>(q, k, c, stats);
  transpose_all_kernel<<<dim3(64, 8, 12), 256, 0, stream>>>(
      q, k, s, stats, qT_all, kT_all, sT_all);
  proj_qk_all_kernel<<<dim3(32, 4, 8), 256, 0, stream>>>(
      qT_all, kT_all, Whq, Whk, bq, bk, qpT, kpT);
  proj_s_all_kernel<<<dim3(32, 4, 4), 256, 0, stream>>>(Whs, sT_all, bs, spp);

  // ---- phase 2: attention (per batch, chunked over i) ----
  const size_t sppB = (size_t)4 * C * L;   // per-batch spp stride (elements)
  for (int b = 0; b < B; b++) {
    for (int ibase = 0; ibase < L; ibase += n_ch) {
      qk_kernel<<<dim3(32, n_ch / 128), 256, 0, stream>>>(
          qpT + (size_t)b * L * C, kpT + (size_t)b * L * C, Sc, ibase);
      softmax_kernel<<<n_ch, 256, 0, stream>>>(Sc, Ph);
      pv_fin_kernel<<<dim3(16, n_ch / 128), 256, 0, stream>>>(
          Ph, spp + (size_t)b * sppB, c + (size_t)b * C * L,
          stats + 8192 + (size_t)b * C * 2, out + (size_t)b * C * L, ibase);
    }
  }
}